// Round 2
// baseline (552.233 us; speedup 1.0000x reference)
//
#include <hip/hip_runtime.h>
#include <stdint.h>

// BitNet MLP: x[65536,512] --int8gemm--> h[65536,2048] --relu^2+SubLN+actquant-->
//             h_q[65536,2048] --int8gemm--> out[65536,512]
// GEMM1 runs twice (stats pass, then quant pass) to avoid materializing h in HBM.
// All reductions deterministic (no atomics) so quantization boundaries are
// stable across graph replays / revalidation.

typedef int v4i __attribute__((ext_vector_type(4)));

#define AS1(p) ((const __attribute__((address_space(1))) void*)(p))
#define AS3(p) ((__attribute__((address_space(3))) void*)(p))

static constexpr size_t OFF_PART = 256;                    // 2*256 doubles = 4096 B
static constexpr size_t OFF_SX   = 8192;
static constexpr size_t OFF_RSQ  = OFF_SX   + 262144;
static constexpr size_t OFF_S2   = OFF_RSQ  + 262144;
static constexpr size_t OFF_INV2 = OFF_S2   + 262144;
static constexpr size_t OFF_WUQ  = OFF_INV2 + 262144;
static constexpr size_t OFF_WDQ  = OFF_WUQ  + 1048576;
static constexpr size_t OFF_XQ   = OFF_WDQ  + 1048576;
static constexpr size_t OFF_HQ   = OFF_XQ   + 33554432;
static constexpr size_t OFF_SS   = OFF_HQ   + 134217728;
static constexpr size_t OFF_MM   = OFF_SS   + 8388608;
// total ws usage = OFF_MM + 8388608  (~179 MB)

// ---------------- weight |w| partial sums (deterministic, fp64) -------------
__global__ void wabs_partial(const float* __restrict__ w, double* __restrict__ part)
{
    int t = threadIdx.x, bid = blockIdx.x;
    const float4* w4 = (const float4*)w;
    int base = bid * 256 + t;
    double s = 0.0;
    #pragma unroll
    for (int j = 0; j < 4; ++j) {                 // 256 blk * 256 thr * 4 = 262144 f4
        float4 v = w4[base + j * 65536];
        s += (double)fabsf(v.x) + (double)fabsf(v.y)
           + (double)fabsf(v.z) + (double)fabsf(v.w);
    }
    #pragma unroll
    for (int off = 32; off > 0; off >>= 1) s += __shfl_down(s, off);
    __shared__ double ps[4];
    int l = t & 63, wv = t >> 6;
    if (l == 0) ps[wv] = s;
    __syncthreads();
    if (t == 0) part[bid] = ((ps[0] + ps[1]) + ps[2]) + ps[3];
}

// ---------------- finalize both weight sums (single block, deterministic) ---
__global__ void finalize_sums(const double* __restrict__ part, double* __restrict__ sums)
{
    int t = threadIdx.x;
    double a = part[t];          // w_up partials
    double b = part[256 + t];    // w_down partials
    #pragma unroll
    for (int off = 32; off > 0; off >>= 1) {
        a += __shfl_down(a, off);
        b += __shfl_down(b, off);
    }
    __shared__ double pa[4], pb[4];
    int l = t & 63, wv = t >> 6;
    if (l == 0) { pa[wv] = a; pb[wv] = b; }
    __syncthreads();
    if (t == 0) {
        sums[0] = ((pa[0] + pa[1]) + pa[2]) + pa[3];
        sums[1] = ((pb[0] + pb[1]) + pb[2]) + pb[3];
    }
}

// ---------------- ternary weight quantization -------------------------------
__global__ void wquant(const float* __restrict__ w, const double* __restrict__ sum,
                       signed char* __restrict__ wq)
{
    int i = blockIdx.x * blockDim.x + threadIdx.x;   // float4 index, n4 = 262144
    if (i >= 262144) return;
    float mean  = (float)(*sum) * (1.0f / 1048576.0f);
    float scale = 1.0f / fmaxf(mean, 1e-5f);
    float4 v = ((const float4*)w)[i];
    int q0 = (int)fminf(fmaxf(rintf(v.x * scale), -1.f), 1.f);
    int q1 = (int)fminf(fmaxf(rintf(v.y * scale), -1.f), 1.f);
    int q2 = (int)fminf(fmaxf(rintf(v.z * scale), -1.f), 1.f);
    int q3 = (int)fminf(fmaxf(rintf(v.w * scale), -1.f), 1.f);
    unsigned pk = (q0 & 255) | ((q1 & 255) << 8) | ((q2 & 255) << 16) | ((q3 & 255) << 24);
    ((unsigned*)wq)[i] = pk;
}

// ---------------- activation quantization of x (per-token, H=512) -----------
__global__ void xquant(const float* __restrict__ x, signed char* __restrict__ xq,
                       float* __restrict__ inv_sx)
{
    int row = blockIdx.x * 4 + (threadIdx.x >> 6);
    int l   = threadIdx.x & 63;
    const float* xr = x + (size_t)row * 512;
    float4 v0 = *(const float4*)(xr + l * 8);
    float4 v1 = *(const float4*)(xr + l * 8 + 4);
    float m = fmaxf(fmaxf(fmaxf(fabsf(v0.x), fabsf(v0.y)), fmaxf(fabsf(v0.z), fabsf(v0.w))),
                    fmaxf(fmaxf(fabsf(v1.x), fabsf(v1.y)), fmaxf(fabsf(v1.z), fabsf(v1.w))));
    #pragma unroll
    for (int off = 1; off < 64; off <<= 1) m = fmaxf(m, __shfl_xor(m, off));
    float mc = fmaxf(m, 1e-5f);
    float s  = 127.0f / mc;
    int q[8];
    q[0] = (int)fminf(fmaxf(rintf(v0.x * s), -128.f), 127.f);
    q[1] = (int)fminf(fmaxf(rintf(v0.y * s), -128.f), 127.f);
    q[2] = (int)fminf(fmaxf(rintf(v0.z * s), -128.f), 127.f);
    q[3] = (int)fminf(fmaxf(rintf(v0.w * s), -128.f), 127.f);
    q[4] = (int)fminf(fmaxf(rintf(v1.x * s), -128.f), 127.f);
    q[5] = (int)fminf(fmaxf(rintf(v1.y * s), -128.f), 127.f);
    q[6] = (int)fminf(fmaxf(rintf(v1.z * s), -128.f), 127.f);
    q[7] = (int)fminf(fmaxf(rintf(v1.w * s), -128.f), 127.f);
    uint2 pk;
    pk.x = (q[0] & 255) | ((q[1] & 255) << 8) | ((q[2] & 255) << 16) | ((q[3] & 255) << 24);
    pk.y = (q[4] & 255) | ((q[5] & 255) << 8) | ((q[6] & 255) << 16) | ((q[7] & 255) << 24);
    *(uint2*)(xq + (size_t)row * 512 + l * 8) = pk;
    if (l == 0) inv_sx[row] = mc * (1.0f / 127.0f);
}

// ---------------- per-row stats reduce: var -> rsqrt, act scale -------------
__global__ void row_reduce(const float* __restrict__ ss_p, const float* __restrict__ mm_p,
                           float* __restrict__ rsq, float* __restrict__ s2,
                           float* __restrict__ inv2)
{
    int row = blockIdx.x * blockDim.x + threadIdx.x;   // grid covers 65536
    float ss = 0.f, mm = 0.f;
    #pragma unroll
    for (int p = 0; p < 32; ++p) {
        ss += ss_p[(size_t)row * 32 + p];
        mm  = fmaxf(mm, mm_p[(size_t)row * 32 + p]);
    }
    float var  = ss * (1.0f / 2048.0f);
    float r    = 1.0f / sqrtf(var + 1e-6f);
    float maxy = fmaxf(r * mm, 1e-5f);
    rsq[row]  = r;
    s2[row]   = 127.0f / maxy;
    inv2[row] = maxy * (1.0f / 127.0f);
}

// ---------------- int8 GEMM: C[M,N] = A[M,K] * B[N,K]^T ---------------------
// EPI 0: stats partials (sum h^2, max|h*g| per row per 64-col slice)
// EPI 1: relu^2 + SubLN + act_quant -> h_q int8
// EPI 2: dequant -> fp32 out
template<int K, int N, int EPI>
__global__ __launch_bounds__(256, 2)
void gemm_i8(const signed char* __restrict__ A,
             const signed char* __restrict__ B,
             const float* __restrict__ rowscale,  // inv_sx (EPI0/1) or inv2 (EPI2)
             const double* __restrict__ wsum,
             const float* __restrict__ g,
             const float* __restrict__ rsq,
             const float* __restrict__ s2,
             float* __restrict__ st_ss,
             float* __restrict__ st_mm,
             signed char* __restrict__ hq,
             float* __restrict__ out)
{
    constexpr int NBN = N / 128;
    __shared__ __align__(16) signed char lA[128 * 64];
    __shared__ __align__(16) signed char lB[128 * 64];

    // bijective XCD-chunked swizzle (m204); N-inner so chunks share A panels
    int nwg  = gridDim.x;
    int orig = blockIdx.x;
    int q8 = nwg >> 3, r8 = nwg & 7;
    int xcd = orig & 7, lin = orig >> 3;
    int swz = (xcd < r8 ? xcd * (q8 + 1) : r8 * (q8 + 1) + (xcd - r8) * q8) + lin;
    int mt = swz / NBN, nt = swz - mt * NBN;

    size_t mbase = (size_t)mt * 128;
    int    nbase = nt * 128;

    int t = threadIdx.x;
    int l = t & 63;
    int wid = t >> 6;
    int wr = wid >> 1, wc = wid & 1;

    v4i acc[4][4] = {};

    const signed char* Ab = A + mbase * K;
    const signed char* Bb = B + (size_t)nbase * K;

    for (int k0 = 0; k0 < K; k0 += 64) {
        // stage 128x64 tiles; LDS dest linear, global source inverse-swizzled
        // (16B-column c XOR row&3); swizzled ds_read below undoes it (rule #21).
        #pragma unroll
        for (int i = 0; i < 2; ++i) {
            int lin16 = i * 256 + t;
            int row   = lin16 >> 2;
            int c     = (lin16 & 3) ^ (row & 3);
            __builtin_amdgcn_global_load_lds(AS1(Ab + (size_t)row * K + k0 + c * 16),
                                             AS3(lA + lin16 * 16), 16, 0, 0);
            __builtin_amdgcn_global_load_lds(AS1(Bb + (size_t)row * K + k0 + c * 16),
                                             AS3(lB + lin16 * 16), 16, 0, 0);
        }
        __syncthreads();
        v4i af[4], bf[4];
        #pragma unroll
        for (int r = 0; r < 4; ++r) {
            int arow = wr * 64 + r * 16 + (l & 15);
            int ac   = (l >> 4) ^ (arow & 3);
            af[r] = *reinterpret_cast<const v4i*>(lA + (arow * 4 + ac) * 16);
            int brow = wc * 64 + r * 16 + (l & 15);
            int bc   = (l >> 4) ^ (brow & 3);
            bf[r] = *reinterpret_cast<const v4i*>(lB + (brow * 4 + bc) * 16);
        }
        #pragma unroll
        for (int r = 0; r < 4; ++r)
            #pragma unroll
            for (int c = 0; c < 4; ++c)
                acc[r][c] = __builtin_amdgcn_mfma_i32_16x16x64_i8(af[r], bf[c], acc[r][c], 0, 0, 0);
        __syncthreads();
    }

    float wmean = fmaxf((float)wsum[0] * (1.0f / 1048576.0f), 1e-5f);

    int rsub = wr * 64 + 4 * (l >> 4);   // + rt*16 + reg  -> local row
    int csub = wc * 64 + (l & 15);       // + ct*16        -> local col

    if constexpr (EPI == 2) {
        #pragma unroll
        for (int rt = 0; rt < 4; ++rt)
            #pragma unroll
            for (int reg = 0; reg < 4; ++reg) {
                size_t grow = mbase + rsub + rt * 16 + reg;
                float f = rowscale[grow] * wmean;
                #pragma unroll
                for (int ct = 0; ct < 4; ++ct)
                    out[grow * N + nbase + csub + ct * 16] = (float)acc[rt][ct][reg] * f;
            }
    } else {
        float gv[4];
        #pragma unroll
        for (int ct = 0; ct < 4; ++ct) gv[ct] = g[nbase + csub + ct * 16];

        if constexpr (EPI == 0) {
            float ssv[4][4], mmv[4][4];
            #pragma unroll
            for (int rt = 0; rt < 4; ++rt)
                #pragma unroll
                for (int reg = 0; reg < 4; ++reg) {
                    size_t grow = mbase + rsub + rt * 16 + reg;
                    float f = rowscale[grow] * wmean;
                    float ss = 0.f, mm = 0.f;
                    #pragma unroll
                    for (int ct = 0; ct < 4; ++ct) {
                        float z = (float)acc[rt][ct][reg] * f;
                        float a = fmaxf(z, 0.f);
                        float h = a * a;
                        ss += h * h;
                        mm  = fmaxf(mm, fabsf(h * gv[ct]));
                    }
                    ssv[rt][reg] = ss; mmv[rt][reg] = mm;
                }
            #pragma unroll
            for (int off = 1; off < 16; off <<= 1)
                #pragma unroll
                for (int rt = 0; rt < 4; ++rt)
                    #pragma unroll
                    for (int reg = 0; reg < 4; ++reg) {
                        ssv[rt][reg] += __shfl_xor(ssv[rt][reg], off);
                        mmv[rt][reg]  = fmaxf(mmv[rt][reg], __shfl_xor(mmv[rt][reg], off));
                    }
            if ((l & 15) == 0) {
                int p = nt * 2 + wc;
                #pragma unroll
                for (int rt = 0; rt < 4; ++rt)
                    #pragma unroll
                    for (int reg = 0; reg < 4; ++reg) {
                        size_t grow = mbase + rsub + rt * 16 + reg;
                        st_ss[grow * 32 + p] = ssv[rt][reg];
                        st_mm[grow * 32 + p] = mmv[rt][reg];
                    }
            }
        } else {  // EPI == 1
            #pragma unroll
            for (int rt = 0; rt < 4; ++rt)
                #pragma unroll
                for (int reg = 0; reg < 4; ++reg) {
                    size_t grow = mbase + rsub + rt * 16 + reg;
                    float f  = rowscale[grow] * wmean;
                    float rq = rsq[grow];
                    float sc = s2[grow];
                    #pragma unroll
                    for (int ct = 0; ct < 4; ++ct) {
                        float z = (float)acc[rt][ct][reg] * f;
                        float a = fmaxf(z, 0.f);
                        float h = a * a;
                        float y = (h * rq) * gv[ct];
                        int q = (int)fminf(fmaxf(rintf(y * sc), -128.f), 127.f);
                        hq[grow * 2048 + nbase + csub + ct * 16] = (signed char)q;
                    }
                }
        }
    }
}

// ---------------------------------------------------------------------------
extern "C" void kernel_launch(void* const* d_in, const int* in_sizes, int n_in,
                              void* d_out, int out_size, void* d_ws, size_t ws_size,
                              hipStream_t stream)
{
    const float* x  = (const float*)d_in[0];
    const float* wu = (const float*)d_in[1];
    const float* wd = (const float*)d_in[2];
    const float* g  = (const float*)d_in[3];
    float* out = (float*)d_out;
    char*  ws  = (char*)d_ws;

    double* sums     = (double*)ws;
    double* part     = (double*)(ws + OFF_PART);    // [0:256)=w_up, [256:512)=w_down
    float*  inv_sx   = (float*)(ws + OFF_SX);
    float*  rsq      = (float*)(ws + OFF_RSQ);
    float*  s2       = (float*)(ws + OFF_S2);
    float*  inv2     = (float*)(ws + OFF_INV2);
    signed char* wuq = (signed char*)(ws + OFF_WUQ);
    signed char* wdq = (signed char*)(ws + OFF_WDQ);
    signed char* xq  = (signed char*)(ws + OFF_XQ);
    signed char* hq  = (signed char*)(ws + OFF_HQ);
    float*  st_ss    = (float*)(ws + OFF_SS);
    float*  st_mm    = (float*)(ws + OFF_MM);

    wabs_partial<<<256, 256, 0, stream>>>(wu, part);
    wabs_partial<<<256, 256, 0, stream>>>(wd, part + 256);
    finalize_sums<<<1, 256, 0, stream>>>(part, sums);
    wquant<<<1024, 256, 0, stream>>>(wu, sums + 0, wuq);
    wquant<<<1024, 256, 0, stream>>>(wd, sums + 1, wdq);
    xquant<<<16384, 256, 0, stream>>>(x, xq, inv_sx);

    // GEMM1 pass A: stats only
    gemm_i8<512, 2048, 0><<<8192, 256, 0, stream>>>(xq, wuq, inv_sx, sums + 0, g,
                                                    nullptr, nullptr, st_ss, st_mm,
                                                    nullptr, nullptr);
    row_reduce<<<256, 256, 0, stream>>>(st_ss, st_mm, rsq, s2, inv2);
    // GEMM1 pass B: fused relu^2 + SubLN + act_quant -> h_q
    gemm_i8<512, 2048, 1><<<8192, 256, 0, stream>>>(xq, wuq, inv_sx, sums + 0, g,
                                                    rsq, s2, nullptr, nullptr,
                                                    hq, nullptr);
    // GEMM2: h_q @ w_down^T -> out
    gemm_i8<2048, 512, 2><<<2048, 256, 0, stream>>>(hq, wdq, inv2, sums + 1,
                                                    nullptr, nullptr, nullptr,
                                                    nullptr, nullptr, nullptr, out);
}